// Round 1
// baseline (57.773 us; speedup 1.0000x reference)
//
#include <hip/hip_runtime.h>
#include <math.h>

// DMLoss fused kernel for MI355X (gfx950).
// B=1024, N=128 pred points, M=128 gt points, INTERP=10 -> 1280 interp points.
// Shapes: ini_pred_poly (B,N,2) f32, pred_poly (B,N,2) f32, gt_poly (B,M,2) f32,
//         keyPointsMask (B,M) f32. Output: scalar f32.

#define BB    1024
#define NN    128
#define MM    128
#define NITP  1280   // MM * 10

__device__ __forceinline__ float sl1(float x) {
    float d = fabsf(x);
    return d < 1.0f ? 0.5f * d * d : d - 0.5f;
}

__global__ void __launch_bounds__(256)
dmloss_main(const float* __restrict__ ini, const float* __restrict__ pred,
            const float* __restrict__ gt,  const float* __restrict__ kmask,
            float4* __restrict__ partials)
{
    const int b   = blockIdx.x;
    const int tid = threadIdx.x;

    __shared__ float4 s_ig[NITP];   // (-2*gx, -2*gy, gx^2+gy^2, 0) per interp point
    __shared__ float2 s_gt[MM];     // raw gt points
    __shared__ float4 s_ii[NN];     // (ix, iy, ix^2+iy^2, 0) per ini_pred point
    __shared__ float  s_rv[256];
    __shared__ int    s_ri[256];
    __shared__ float  s_sum[3][4];

    const float2* gt2 = (const float2*)(gt   + (size_t)b * MM * 2);
    const float2* in2 = (const float2*)(ini  + (size_t)b * NN * 2);
    const float2* pr2 = (const float2*)(pred + (size_t)b * NN * 2);

    if (tid < MM) {
        float2 g = gt2[tid];
        s_gt[tid] = g;
        float2 p = in2[tid];
        s_ii[tid] = make_float4(p.x, p.y, p.x * p.x + p.y * p.y, 0.0f);
    }
    __syncthreads();

    // Build interp table: i = m*10 + j; interp = gt[m]*s + gt[m-1]*(1-s), s=j/10.
    for (int i = tid; i < NITP; i += 256) {
        int m = i / 10;
        int j = i - m * 10;
        float s = (float)j / 10.0f;        // matches arange(10)/10 rounding
        float t = 1.0f - s;
        float2 gm = s_gt[m];
        float2 gp = s_gt[(m + MM - 1) & (MM - 1)];
        float gx = gm.x * s + gp.x * t;
        float gy = gm.y * s + gp.y * t;
        float g2 = gx * gx + gy * gy;
        s_ig[i] = make_float4(-2.0f * gx, -2.0f * gy, g2, 0.0f);
    }
    __syncthreads();

    const int n = tid & 127;
    const int h = tid >> 7;            // 0 or 1: two threads per point
    float sumA = 0.0f, sumB = 0.0f, sumC = 0.0f;

    // ---- Phase B: for each pred point n, argmin over 1280 interp points ----
    {
        float2 p  = in2[n];
        float px = p.x, py = p.y, p2 = px * px + py * py;
        float best = INFINITY;
        int   bidx = 0x7fffffff;
        #pragma unroll 4
        for (int m = h; m < NITP; m += 2) {
            float4 A = s_ig[m];
            float d = fmaf(A.x, px, fmaf(A.y, py, A.z + p2));
            if (d < best) { best = d; bidx = m; }
        }
        s_rv[tid] = best; s_ri[tid] = bidx;
        __syncthreads();
        if (h == 0) {
            float ov = s_rv[tid + 128];
            int   oi = s_ri[tid + 128];
            if (ov < best || (ov == best && oi < bidx)) { best = ov; bidx = oi; }
            float4 A = s_ig[bidx];
            float gx = -0.5f * A.x, gy = -0.5f * A.y;
            float2 pr = pr2[n];
            sumA = sl1(pr.x - gx) + sl1(pr.y - gy);
        }
        __syncthreads();   // protect s_rv/s_ri reuse
    }

    // ---- Phase C: for each gt point m, argmin over 128 ini_pred points ----
    {
        const int m = n;
        float2 g = s_gt[m];
        float ax = -2.0f * g.x, ay = -2.0f * g.y;
        float c  = g.x * g.x + g.y * g.y;
        float best = INFINITY;
        int   bidx = 0x7fffffff;
        #pragma unroll 4
        for (int k = h; k < NN; k += 2) {
            float4 I = s_ii[k];
            float d = fmaf(I.x, ax, fmaf(I.y, ay, I.z + c));
            if (d < best) { best = d; bidx = k; }
        }
        s_rv[tid] = best; s_ri[tid] = bidx;
        __syncthreads();
        if (h == 0) {
            float ov = s_rv[tid + 128];
            int   oi = s_ri[tid + 128];
            if (ov < best || (ov == best && oi < bidx)) { best = ov; bidx = oi; }
            float2 pr = pr2[bidx];
            float w = kmask[b * MM + m];
            sumB = w * (sl1(pr.x - g.x) + sl1(pr.y - g.y));
            sumC = w;
        }
    }

    // ---- Block reduction of (sumA, sumB, sumC) ----
    #pragma unroll
    for (int off = 32; off > 0; off >>= 1) {
        sumA += __shfl_down(sumA, off);
        sumB += __shfl_down(sumB, off);
        sumC += __shfl_down(sumC, off);
    }
    const int wave = tid >> 6, lane = tid & 63;
    if (lane == 0) {
        s_sum[0][wave] = sumA; s_sum[1][wave] = sumB; s_sum[2][wave] = sumC;
    }
    __syncthreads();
    if (tid == 0) {
        float A = 0.0f, Bs = 0.0f, C = 0.0f;
        #pragma unroll
        for (int w = 0; w < 4; ++w) {
            A += s_sum[0][w]; Bs += s_sum[1][w]; C += s_sum[2][w];
        }
        partials[b] = make_float4(A, Bs, C, 0.0f);
    }
}

__global__ void __launch_bounds__(256)
dmloss_final(const float4* __restrict__ partials, float* __restrict__ out)
{
    const int tid = threadIdx.x;
    float A = 0.0f, Bs = 0.0f, C = 0.0f;
    #pragma unroll
    for (int i = tid; i < BB; i += 256) {
        float4 p = partials[i];
        A += p.x; Bs += p.y; C += p.z;
    }
    #pragma unroll
    for (int off = 32; off > 0; off >>= 1) {
        A  += __shfl_down(A, off);
        Bs += __shfl_down(Bs, off);
        C  += __shfl_down(C, off);
    }
    __shared__ float sA[4], sB[4], sC[4];
    const int wave = tid >> 6, lane = tid & 63;
    if (lane == 0) { sA[wave] = A; sB[wave] = Bs; sC[wave] = C; }
    __syncthreads();
    if (tid == 0) {
        float a = sA[0] + sA[1] + sA[2] + sA[3];
        float bs = sB[0] + sB[1] + sB[2] + sB[3];
        float c = sC[0] + sC[1] + sC[2] + sC[3];
        float loss_pred2gt = a / ((float)BB * (float)NN * 2.0f);
        float loss_set2set = bs / (2.0f * c + 1.0f) + loss_pred2gt;
        out[0] = 0.5f * loss_set2set;
    }
}

extern "C" void kernel_launch(void* const* d_in, const int* in_sizes, int n_in,
                              void* d_out, int out_size, void* d_ws, size_t ws_size,
                              hipStream_t stream)
{
    const float* ini   = (const float*)d_in[0];
    const float* pred  = (const float*)d_in[1];
    const float* gt    = (const float*)d_in[2];
    const float* kmask = (const float*)d_in[3];
    float4* partials = (float4*)d_ws;   // 1024 * 16 B = 16 KiB

    dmloss_main<<<dim3(BB), dim3(256), 0, stream>>>(ini, pred, gt, kmask, partials);
    dmloss_final<<<dim3(1), dim3(256), 0, stream>>>(partials, (float*)d_out);
}

// Round 2
// 29.270 us; speedup vs baseline: 1.9738x; 1.9738x over previous
//
#include <hip/hip_runtime.h>
#include <math.h>

// DMLoss fused kernel for MI355X (gfx950).
// B=1024, N=128 pred points, M=128 gt points, INTERP=10 -> 1280 interp points.
// Round 2: Phase B uses per-segment convex-quadratic vertex pruning:
// evaluate only the 2 grid samples adjacent to the vertex (exact table formula),
// instead of all 10. ~3x fewer VALU ops + DS reads in the dominant loop.

#define BB    1024
#define NN    128
#define MM    128
#define NITP  1280   // MM * 10

__device__ __forceinline__ float sl1(float x) {
    float d = fabsf(x);
    return d < 1.0f ? 0.5f * d * d : d - 0.5f;
}

__global__ void __launch_bounds__(256)
dmloss_main(const float* __restrict__ ini, const float* __restrict__ pred,
            const float* __restrict__ gt,  const float* __restrict__ kmask,
            float4* __restrict__ partials)
{
    const int b   = blockIdx.x;
    const int tid = threadIdx.x;

    __shared__ float4 s_ig[NITP];   // (-2*gx, -2*gy, gx^2+gy^2, 0) per interp point
    __shared__ float2 s_gt[MM];     // raw gt points
    __shared__ float4 s_ii[NN];     // (ix, iy, ix^2+iy^2, 0) per ini_pred point
    __shared__ float4 s_seg[MM];    // (ax, ay, ex*10/A, ey*10/A) per segment
    __shared__ float  s_rv[256];
    __shared__ int    s_ri[256];
    __shared__ float  s_sum[3][4];

    const float2* gt2 = (const float2*)(gt   + (size_t)b * MM * 2);
    const float2* in2 = (const float2*)(ini  + (size_t)b * NN * 2);
    const float2* pr2 = (const float2*)(pred + (size_t)b * NN * 2);

    if (tid < MM) {
        float2 g = gt2[tid];
        s_gt[tid] = g;
        float2 p = in2[tid];
        s_ii[tid] = make_float4(p.x, p.y, p.x * p.x + p.y * p.y, 0.0f);
    }
    __syncthreads();

    // Build interp table: i = m*10 + j; interp = gt[m]*s + gt[m-1]*(1-s), s=j/10.
    for (int i = tid; i < NITP; i += 256) {
        int m = i / 10;
        int j = i - m * 10;
        float s = (float)j / 10.0f;        // matches arange(10)/10 rounding
        float t = 1.0f - s;
        float2 gm = s_gt[m];
        float2 gp = s_gt[(m + MM - 1) & (MM - 1)];
        float gx = gm.x * s + gp.x * t;
        float gy = gm.y * s + gp.y * t;
        float g2 = gx * gx + gy * gy;
        s_ig[i] = make_float4(-2.0f * gx, -2.0f * gy, g2, 0.0f);
    }
    // Segment table: segment m runs from a = gt[m-1] (j=0) toward bb = gt[m].
    // Vertex of d(j) (convex quadratic in j) is at j = ((p-a).e) * 10/|e|^2.
    if (tid < MM) {
        float2 a  = s_gt[(tid + MM - 1) & (MM - 1)];
        float2 bp = s_gt[tid];
        float ex = bp.x - a.x, ey = bp.y - a.y;
        float A  = ex * ex + ey * ey;
        float inv = 10.0f / A;             // A==0 -> inf -> jv NaN -> clamps to 0
        s_seg[tid] = make_float4(a.x, a.y, ex * inv, ey * inv);
    }
    __syncthreads();

    const int n = tid & 127;
    const int h = tid >> 7;            // 0 or 1: two threads per point
    float sumA = 0.0f, sumB = 0.0f, sumC = 0.0f;

    // ---- Phase B: for each pred point n, argmin over 1280 interp points ----
    // Per segment, only the two grid samples bracketing the quadratic's vertex
    // can be the segment argmin (convexity). Evaluate those 2 with the exact
    // reference-rounding formula and fold into the running argmin.
    {
        float4 I = s_ii[n];
        float px = I.x, py = I.y, p2 = I.z;
        float best = INFINITY;
        int   bidx = 0x7fffffff;
        int   mb = 10 * h;
        #pragma unroll 4
        for (int m = h; m < MM; m += 2, mb += 20) {
            float4 T = s_seg[m];                       // broadcast
            float qx = px - T.x, qy = py - T.y;
            float jv = fmaf(qx, T.z, qy * T.w);        // vertex in j-units
            float jc = fminf(fmaxf(jv, 0.0f), 8.0f);   // NaN-safe clamp to [0,8]
            int   i0 = mb + (int)jc;                   // trunc == floor (jc>=0)
            float4 c0 = s_ig[i0];
            float4 c1 = s_ig[i0 + 1];
            float d0 = fmaf(c0.x, px, fmaf(c0.y, py, c0.z + p2));
            float d1 = fmaf(c1.x, px, fmaf(c1.y, py, c1.z + p2));
            bool  sec = d1 < d0;                       // tie -> lower index
            float dm = sec ? d1 : d0;
            int   im = sec ? (i0 + 1) : i0;
            if (dm < best) { best = dm; bidx = im; }   // ascending m -> first occurrence
        }
        s_rv[tid] = best; s_ri[tid] = bidx;
        __syncthreads();
        if (h == 0) {
            float ov = s_rv[tid + 128];
            int   oi = s_ri[tid + 128];
            if (ov < best || (ov == best && oi < bidx)) { best = ov; bidx = oi; }
            float4 A = s_ig[bidx];
            float gx = -0.5f * A.x, gy = -0.5f * A.y;
            float2 pr = pr2[n];
            sumA = sl1(pr.x - gx) + sl1(pr.y - gy);
        }
        __syncthreads();   // protect s_rv/s_ri reuse
    }

    // ---- Phase C: for each gt point m, argmin over 128 ini_pred points ----
    {
        const int m = n;
        float2 g = s_gt[m];
        float ax = -2.0f * g.x, ay = -2.0f * g.y;
        float c  = g.x * g.x + g.y * g.y;
        float best = INFINITY;
        int   bidx = 0x7fffffff;
        #pragma unroll 4
        for (int k = h; k < NN; k += 2) {
            float4 I = s_ii[k];
            float d = fmaf(I.x, ax, fmaf(I.y, ay, I.z + c));
            if (d < best) { best = d; bidx = k; }
        }
        s_rv[tid] = best; s_ri[tid] = bidx;
        __syncthreads();
        if (h == 0) {
            float ov = s_rv[tid + 128];
            int   oi = s_ri[tid + 128];
            if (ov < best || (ov == best && oi < bidx)) { best = ov; bidx = oi; }
            float2 pr = pr2[bidx];
            float w = kmask[b * MM + m];
            sumB = w * (sl1(pr.x - g.x) + sl1(pr.y - g.y));
            sumC = w;
        }
    }

    // ---- Block reduction of (sumA, sumB, sumC) ----
    #pragma unroll
    for (int off = 32; off > 0; off >>= 1) {
        sumA += __shfl_down(sumA, off);
        sumB += __shfl_down(sumB, off);
        sumC += __shfl_down(sumC, off);
    }
    const int wave = tid >> 6, lane = tid & 63;
    if (lane == 0) {
        s_sum[0][wave] = sumA; s_sum[1][wave] = sumB; s_sum[2][wave] = sumC;
    }
    __syncthreads();
    if (tid == 0) {
        float A = 0.0f, Bs = 0.0f, C = 0.0f;
        #pragma unroll
        for (int w = 0; w < 4; ++w) {
            A += s_sum[0][w]; Bs += s_sum[1][w]; C += s_sum[2][w];
        }
        partials[b] = make_float4(A, Bs, C, 0.0f);
    }
}

__global__ void __launch_bounds__(256)
dmloss_final(const float4* __restrict__ partials, float* __restrict__ out)
{
    const int tid = threadIdx.x;
    float A = 0.0f, Bs = 0.0f, C = 0.0f;
    #pragma unroll
    for (int i = tid; i < BB; i += 256) {
        float4 p = partials[i];
        A += p.x; Bs += p.y; C += p.z;
    }
    #pragma unroll
    for (int off = 32; off > 0; off >>= 1) {
        A  += __shfl_down(A, off);
        Bs += __shfl_down(Bs, off);
        C  += __shfl_down(C, off);
    }
    __shared__ float sA[4], sB[4], sC[4];
    const int wave = tid >> 6, lane = tid & 63;
    if (lane == 0) { sA[wave] = A; sB[wave] = Bs; sC[wave] = C; }
    __syncthreads();
    if (tid == 0) {
        float a = sA[0] + sA[1] + sA[2] + sA[3];
        float bs = sB[0] + sB[1] + sB[2] + sB[3];
        float c = sC[0] + sC[1] + sC[2] + sC[3];
        float loss_pred2gt = a / ((float)BB * (float)NN * 2.0f);
        float loss_set2set = bs / (2.0f * c + 1.0f) + loss_pred2gt;
        out[0] = 0.5f * loss_set2set;
    }
}

extern "C" void kernel_launch(void* const* d_in, const int* in_sizes, int n_in,
                              void* d_out, int out_size, void* d_ws, size_t ws_size,
                              hipStream_t stream)
{
    const float* ini   = (const float*)d_in[0];
    const float* pred  = (const float*)d_in[1];
    const float* gt    = (const float*)d_in[2];
    const float* kmask = (const float*)d_in[3];
    float4* partials = (float4*)d_ws;   // 1024 * 16 B = 16 KiB

    dmloss_main<<<dim3(BB), dim3(256), 0, stream>>>(ini, pred, gt, kmask, partials);
    dmloss_final<<<dim3(1), dim3(256), 0, stream>>>(partials, (float*)d_out);
}

// Round 3
// 19.624 us; speedup vs baseline: 2.9441x; 1.4916x over previous
//
#include <hip/hip_runtime.h>
#include <math.h>

// DMLoss fused kernel for MI355X (gfx950).
// B=1024, N=128 pred, M=128 gt, INTERP=10 -> 1280 interp points.
// Round 3: table-free Phase B (single vertex-rounded candidate per segment,
// computed inline from segment data), 512-thread blocks (4-way point split)
// for 8 waves/SIMD occupancy, pred points staged in LDS for the Phase C gather.

#define BB    1024
#define NN    128
#define MM    128

__device__ __forceinline__ float sl1(float x) {
    float d = fabsf(x);
    return d < 1.0f ? 0.5f * d * d : d - 0.5f;
}

__global__ void __launch_bounds__(512, 8)
dmloss_main(const float* __restrict__ ini, const float* __restrict__ pred,
            const float* __restrict__ gt,  const float* __restrict__ kmask,
            float4* __restrict__ partials)
{
    const int b   = blockIdx.x;
    const int tid = threadIdx.x;
    const int n   = tid & 127;   // owned point (pred in B, gt in C)
    const int h   = tid >> 7;    // 0..3: 4-way split of the scan dimension

    __shared__ float2 s_gt[MM];      // raw gt points
    __shared__ float4 s_ii[NN];      // (ix, iy, k_float, 0) ini_pred points
    __shared__ float2 s_pr[NN];      // pred points (for Phase C gather)
    __shared__ float4 s_segA[MM];    // (ax, ay, ex, ey): a=gt[m-1], e=gt[m]-a
    __shared__ float4 s_segB[MM];    // (ex*10/A, ey*10/A, -(a.e)*10/A, m*10f)
    __shared__ float  s_step[16];    // exact j/10 values
    __shared__ float  s_rv[512];
    __shared__ float  s_rf[512];
    __shared__ float  s_sum[3][8];

    const float2* gt2 = (const float2*)(gt   + (size_t)b * MM * 2);
    const float2* in2 = (const float2*)(ini  + (size_t)b * NN * 2);
    const float2* pr2 = (const float2*)(pred + (size_t)b * NN * 2);

    float2 myPr = make_float2(0.f, 0.f);
    float  myKm = 0.f;

    if (tid < 128) {
        s_gt[tid] = gt2[tid];
        myPr = pr2[tid];               // preload for epilogue A
        myKm = kmask[b * MM + tid];    // preload for epilogue C
    } else if (tid < 256) {
        int k = tid - 128;
        float2 p = in2[k];
        s_ii[k] = make_float4(p.x, p.y, (float)k, 0.0f);
    } else if (tid < 384) {
        int k = tid - 256;
        s_pr[k] = pr2[k];
    } else if (tid < 400) {
        int j = tid - 384;
        s_step[j] = (float)j / 10.0f;  // exact IEEE division
    }
    __syncthreads();

    // Segment tables. Segment m: a = gt[m-1] (j=0) -> gt[m] (j=10).
    // Vertex of the (convex) squared-distance quadratic: jv = ((p-a).e)*10/|e|^2.
    if (tid < 128) {
        float2 a  = s_gt[(tid + 127) & 127];
        float2 gm = s_gt[tid];
        float ex = gm.x - a.x, ey = gm.y - a.y;
        float A  = ex * ex + ey * ey;
        float inv = 10.0f / A;                 // A==0 -> inf -> jv NaN -> clamp 0
        float exi = ex * inv, eyi = ey * inv;
        float aei = -(a.x * exi + a.y * eyi);
        s_segA[tid] = make_float4(a.x, a.y, ex, ey);
        s_segB[tid] = make_float4(exi, eyi, aei, (float)(tid * 10));
    }
    __syncthreads();

    float4 I0 = s_ii[n];
    const float px = I0.x, py = I0.y;
    float sumA = 0.0f, sumB = 0.0f, sumC = 0.0f;

    // ---- Phase B: per pred point, argmin over 1280 interp points ----
    // Grid argmin on segment m is at round(clamp(jv,0,9)) by symmetry of the
    // quadratic; evaluate that single candidate. Segment data is wave-uniform
    // (h is constant per wave) -> broadcast LDS reads.
    float best = INFINITY, bf = 1e30f;
    {
        #pragma unroll 4
        for (int m = h; m < MM; m += 4) {
            float4 T2 = s_segB[m];
            float4 T1 = s_segA[m];
            float jv = fmaf(px, T2.x, fmaf(py, T2.y, T2.z));
            float jc = fminf(fmaxf(jv, 0.0f), 9.0f);   // NaN-safe clamp
            float jr = rintf(jc);                      // v_rndne
            float s  = jr * 0.1f;
            float gx = fmaf(T1.z, s, T1.x);
            float gy = fmaf(T1.w, s, T1.y);
            float dx = gx - px, dy = gy - py;
            float d  = fmaf(dx, dx, dy * dy);
            float fi = T2.w + jr;                      // exact integer float
            bool better = d < best;                    // ascending m -> first occ.
            best = better ? d : best;
            bf   = better ? fi : bf;
        }
        s_rv[tid] = best; s_rf[tid] = bf;
    }
    __syncthreads();
    if (h == 0) {
        #pragma unroll
        for (int q = 1; q < 4; ++q) {
            float ov = s_rv[n + 128 * q];
            float of = s_rf[n + 128 * q];
            if (ov < best || (ov == best && of < bf)) { best = ov; bf = of; }
        }
        int bidx = (int)bf;
        int m = bidx / 10;
        int j = bidx - m * 10;
        float s = s_step[j];
        float t = 1.0f - s;
        float2 gm = s_gt[m];
        float2 gp = s_gt[(m + 127) & 127];
        float gx = gm.x * s + gp.x * t;     // exact reference interp formula
        float gy = gm.y * s + gp.y * t;
        sumA = sl1(myPr.x - gx) + sl1(myPr.y - gy);
    }
    __syncthreads();   // protect s_rv/s_rf reuse

    // ---- Phase C: per gt point, argmin over 128 ini_pred points ----
    {
        float2 g = s_gt[n];
        best = INFINITY; bf = 1e30f;
        #pragma unroll 4
        for (int k = h; k < NN; k += 4) {
            float4 Ik = s_ii[k];                       // broadcast
            float dx = Ik.x - g.x, dy = Ik.y - g.y;
            float d  = fmaf(dx, dx, dy * dy);
            bool better = d < best;
            best = better ? d : best;
            bf   = better ? Ik.z : bf;
        }
        s_rv[tid] = best; s_rf[tid] = bf;
        __syncthreads();
        if (h == 0) {
            #pragma unroll
            for (int q = 1; q < 4; ++q) {
                float ov = s_rv[n + 128 * q];
                float of = s_rf[n + 128 * q];
                if (ov < best || (ov == best && of < bf)) { best = ov; bf = of; }
            }
            int k = (int)bf;
            float2 pk = s_pr[k];
            sumB = myKm * (sl1(pk.x - g.x) + sl1(pk.y - g.y));
            sumC = myKm;
        }
    }

    // ---- Block reduction of (sumA, sumB, sumC) ----
    #pragma unroll
    for (int off = 32; off > 0; off >>= 1) {
        sumA += __shfl_down(sumA, off);
        sumB += __shfl_down(sumB, off);
        sumC += __shfl_down(sumC, off);
    }
    const int wave = tid >> 6, lane = tid & 63;
    if (lane == 0) {
        s_sum[0][wave] = sumA; s_sum[1][wave] = sumB; s_sum[2][wave] = sumC;
    }
    __syncthreads();
    if (tid == 0) {
        float A = 0.0f, Bs = 0.0f, C = 0.0f;
        #pragma unroll
        for (int w = 0; w < 8; ++w) {
            A += s_sum[0][w]; Bs += s_sum[1][w]; C += s_sum[2][w];
        }
        partials[b] = make_float4(A, Bs, C, 0.0f);
    }
}

__global__ void __launch_bounds__(256)
dmloss_final(const float4* __restrict__ partials, float* __restrict__ out)
{
    const int tid = threadIdx.x;
    float A = 0.0f, Bs = 0.0f, C = 0.0f;
    #pragma unroll
    for (int i = tid; i < BB; i += 256) {
        float4 p = partials[i];
        A += p.x; Bs += p.y; C += p.z;
    }
    #pragma unroll
    for (int off = 32; off > 0; off >>= 1) {
        A  += __shfl_down(A, off);
        Bs += __shfl_down(Bs, off);
        C  += __shfl_down(C, off);
    }
    __shared__ float sA[4], sB[4], sC[4];
    const int wave = tid >> 6, lane = tid & 63;
    if (lane == 0) { sA[wave] = A; sB[wave] = Bs; sC[wave] = C; }
    __syncthreads();
    if (tid == 0) {
        float a  = sA[0] + sA[1] + sA[2] + sA[3];
        float bs = sB[0] + sB[1] + sB[2] + sB[3];
        float c  = sC[0] + sC[1] + sC[2] + sC[3];
        float loss_pred2gt = a / ((float)BB * (float)NN * 2.0f);
        float loss_set2set = bs / (2.0f * c + 1.0f) + loss_pred2gt;
        out[0] = 0.5f * loss_set2set;
    }
}

extern "C" void kernel_launch(void* const* d_in, const int* in_sizes, int n_in,
                              void* d_out, int out_size, void* d_ws, size_t ws_size,
                              hipStream_t stream)
{
    const float* ini   = (const float*)d_in[0];
    const float* pred  = (const float*)d_in[1];
    const float* gt    = (const float*)d_in[2];
    const float* kmask = (const float*)d_in[3];
    float4* partials = (float4*)d_ws;   // 1024 * 16 B = 16 KiB

    dmloss_main<<<dim3(BB), dim3(512), 0, stream>>>(ini, pred, gt, kmask, partials);
    dmloss_final<<<dim3(1), dim3(256), 0, stream>>>(partials, (float*)d_out);
}